// Round 4
// baseline (241.423 us; speedup 1.0000x reference)
//
#include <hip/hip_runtime.h>
#include <math.h>

// HR_HLIFLayer2D: leaky integrate-and-fire over T=32 timesteps.
// x: (B=16, T=32, C=64, H=32, W=32) f32; vth_raw/decay_raw: (C,H,W) f32.
// out: spikes (B,T,C,H,W) f32 in {0.0, 1.0}.
//
// R4: float4/thread (16 B/lane coalescing sweet spot, half the memory-instr
// count of R3's float2), 1024 blocks = 4 blocks/CU = 16 waves/CU, explicit
// depth-6 rotating prefetch (5 x 1 KB loads in flight/wave = 80 KB/CU
// outstanding, ~8x the latency-coverage requirement), non-temporal stores.
//
// Numerics: recurrence uses explicit __fmul_rn/__fadd_rn/__fsub_rn to match
// the fp32 reference op order exactly (no FMA contraction). Params computed
// with double transcendentals, rounded once to fp32 per reference op sequence.
// absmax == 0.0 verified in R1-R3 with this exact scheme.

#define LIF_B    16
#define LIF_T    32
#define LIF_CHW  65536   // 64*32*32
#define LIF_CHW4 16384   // CHW / 4
#define PF_DEPTH 6

typedef float vf4 __attribute__((ext_vector_type(4)));

__global__ __launch_bounds__(256) void HR_HLIFLayer2D_kernel(
    const float* __restrict__ x,
    const float* __restrict__ vth_raw,
    const float* __restrict__ decay_raw,
    float* __restrict__ out)
{
    const int g = blockIdx.x * 256 + threadIdx.x;   // [0, B*CHW4)
    const int b = g >> 14;                          // g / CHW4
    const int j = g & (LIF_CHW4 - 1);               // float4 index within CHW

    const vf4 vr4 = reinterpret_cast<const vf4*>(vth_raw)[j];
    const vf4 dr4 = reinterpret_cast<const vf4*>(decay_raw)[j];
    const float vrr[4] = {vr4.x, vr4.y, vr4.z, vr4.w};
    const float drr[4] = {dr4.x, dr4.y, dr4.z, dr4.w};

    const size_t base4 = (size_t)b * (LIF_T * LIF_CHW4) + (size_t)j;
    const vf4* __restrict__ x4 = reinterpret_cast<const vf4*>(x);
    vf4* __restrict__ o4 = reinterpret_cast<vf4*>(out);

    // Kick off the prefetch pipeline BEFORE the (expensive, double-precision)
    // param math so the loads overlap it.
    vf4 pf[PF_DEPTH];
#pragma unroll
    for (int t = 0; t < PF_DEPTH - 1; ++t)
        pf[t] = x4[base4 + (size_t)t * LIF_CHW4];

    float vth[4], dec[4];
#pragma unroll
    for (int i = 0; i < 4; ++i) {
        // vth = softplus(vth_raw*0.1 + 0.5) + 0.01, fp32 rounding sequence
        float a  = __fmul_rn(vrr[i], 0.1f);
        float bb = __fadd_rn(a, 0.5f);
        double sp = log1p(exp((double)bb));          // correctly-rounded softplus
        vth[i] = __fadd_rn((float)sp, 0.01f);

        // decay = clip(sigmoid(decay_raw*0.1 + 2.0), 0, 0.99)
        float z = __fmul_rn(drr[i], 0.1f);
        float w = __fadd_rn(z, 2.0f);
        double sg = 1.0 / (1.0 + exp(-(double)w));
        float sgf = (float)sg;
        sgf = fminf(fmaxf(sgf, 0.0f), 0.99f);        // never binds in practice
        dec[i] = sgf;
    }

    float v[4] = {0.f, 0.f, 0.f, 0.f};

#pragma unroll
    for (int t = 0; t < LIF_T; ++t) {
        if (t + PF_DEPTH - 1 < LIF_T)                 // compile-time (full unroll)
            pf[(t + PF_DEPTH - 1) % PF_DEPTH] =
                x4[base4 + (size_t)(t + PF_DEPTH - 1) * LIF_CHW4];

        const vf4 xt = pf[t % PF_DEPTH];
        const float xi[4] = {xt.x, xt.y, xt.z, xt.w};
        vf4 s;
        float so[4];
#pragma unroll
        for (int i = 0; i < 4; ++i) {
            // v = v*decay + x_t   (separate mul, add — match ref rounding)
            float vv = __fadd_rn(__fmul_rn(v[i], dec[i]), xi[i]);
            // s = (v - vth > 0) ? 1 : 0
            float d = __fsub_rn(vv, vth[i]);
            bool fire = (d > 0.0f);
            so[i] = fire ? 1.0f : 0.0f;
            // v = v - s*vth: s=1 -> exactly d (fl(v - vth)); s=0 -> exactly vv
            v[i] = fire ? d : vv;
        }
        s.x = so[0]; s.y = so[1]; s.z = so[2]; s.w = so[3];
        __builtin_nontemporal_store(s, &o4[base4 + (size_t)t * LIF_CHW4]);
    }
}

extern "C" void kernel_launch(void* const* d_in, const int* in_sizes, int n_in,
                              void* d_out, int out_size, void* d_ws, size_t ws_size,
                              hipStream_t stream) {
    const float* x         = (const float*)d_in[0];
    const float* vth_raw   = (const float*)d_in[1];
    const float* decay_raw = (const float*)d_in[2];
    float* out             = (float*)d_out;

    const int total_threads = LIF_B * LIF_CHW4;   // 262144
    const int block = 256;
    const int grid = total_threads / block;       // 1024 blocks = 4 blocks/CU
    HR_HLIFLayer2D_kernel<<<grid, block, 0, stream>>>(x, vth_raw, decay_raw, out);
}

// Round 5
// 237.380 us; speedup vs baseline: 1.0170x; 1.0170x over previous
//
#include <hip/hip_runtime.h>
#include <math.h>

// HR_HLIFLayer2D: leaky integrate-and-fire over T=32 timesteps.
// x: (B=16, T=32, C=64, H=32, W=32) f32; vth_raw/decay_raw: (C,H,W) f32.
// out: spikes (B,T,C,H,W) f32 in {0.0, 1.0}.
//
// R5: the R1-R4 counters all showed VGPR_Count=32 -> the compiler was sinking
// prefetch loads to their uses (register-pressure heuristic), leaving ~1-2
// loads in flight per wave (~16 KB/CU, latency-bound at ~2.4 TB/s).
// Fix: (a) __launch_bounds__(256,4) raises the VGPR budget to 128 so the
// allocator may hold a depth-8 float4 pipeline; (b) sched_barrier(0) after
// each prefetch load pins issue order (load t+7 before compute/store t).
// Steady state: 7 x 1 KB loads in flight/wave = 112 KB/CU outstanding.
//
// Numerics: recurrence uses explicit __fmul_rn/__fadd_rn/__fsub_rn to match
// the fp32 reference op order exactly (no FMA contraction). Params computed
// with double transcendentals, rounded once to fp32 per reference op sequence.
// absmax == 0.0 verified in R1-R4 with this exact scheme.

#define LIF_B    16
#define LIF_T    32
#define LIF_CHW  65536   // 64*32*32
#define LIF_CHW4 16384   // CHW / 4
#define PF_DEPTH 8

typedef float vf4 __attribute__((ext_vector_type(4)));

__global__ __launch_bounds__(256, 4) void HR_HLIFLayer2D_kernel(
    const float* __restrict__ x,
    const float* __restrict__ vth_raw,
    const float* __restrict__ decay_raw,
    float* __restrict__ out)
{
    const int g = blockIdx.x * 256 + threadIdx.x;   // [0, B*CHW4)
    const int b = g >> 14;                          // g / CHW4
    const int j = g & (LIF_CHW4 - 1);               // float4 index within CHW

    const size_t base4 = (size_t)b * (LIF_T * LIF_CHW4) + (size_t)j;
    const vf4* __restrict__ x4 = reinterpret_cast<const vf4*>(x);
    vf4* __restrict__ o4 = reinterpret_cast<vf4*>(out);

    // Fill the pipeline: issue loads t=0..PF_DEPTH-2, pinned in place by
    // sched_barrier so they overlap the double-precision param prologue.
    vf4 pf[PF_DEPTH];
#pragma unroll
    for (int t = 0; t < PF_DEPTH - 1; ++t) {
        pf[t] = x4[base4 + (size_t)t * LIF_CHW4];
        __builtin_amdgcn_sched_barrier(0);
    }

    const vf4 vr4 = reinterpret_cast<const vf4*>(vth_raw)[j];
    const vf4 dr4 = reinterpret_cast<const vf4*>(decay_raw)[j];
    const float vrr[4] = {vr4.x, vr4.y, vr4.z, vr4.w};
    const float drr[4] = {dr4.x, dr4.y, dr4.z, dr4.w};

    float vth[4], dec[4];
#pragma unroll
    for (int i = 0; i < 4; ++i) {
        // vth = softplus(vth_raw*0.1 + 0.5) + 0.01, fp32 rounding sequence
        float a  = __fmul_rn(vrr[i], 0.1f);
        float bb = __fadd_rn(a, 0.5f);
        double sp = log1p(exp((double)bb));          // correctly-rounded softplus
        vth[i] = __fadd_rn((float)sp, 0.01f);

        // decay = clip(sigmoid(decay_raw*0.1 + 2.0), 0, 0.99)
        float z = __fmul_rn(drr[i], 0.1f);
        float w = __fadd_rn(z, 2.0f);
        double sg = 1.0 / (1.0 + exp(-(double)w));
        float sgf = (float)sg;
        sgf = fminf(fmaxf(sgf, 0.0f), 0.99f);        // never binds in practice
        dec[i] = sgf;
    }

    float v[4] = {0.f, 0.f, 0.f, 0.f};

#pragma unroll
    for (int t = 0; t < LIF_T; ++t) {
        // Issue the load PF_DEPTH-1 steps ahead, then fence the scheduler so
        // it cannot sink this load below the compute/store of step t.
        if (t + PF_DEPTH - 1 < LIF_T) {               // compile-time (full unroll)
            pf[(t + PF_DEPTH - 1) % PF_DEPTH] =
                x4[base4 + (size_t)(t + PF_DEPTH - 1) * LIF_CHW4];
            __builtin_amdgcn_sched_barrier(0);
        }

        const vf4 xt = pf[t % PF_DEPTH];
        const float xi[4] = {xt.x, xt.y, xt.z, xt.w};
        vf4 s;
        float so[4];
#pragma unroll
        for (int i = 0; i < 4; ++i) {
            // v = v*decay + x_t   (separate mul, add — match ref rounding)
            float vv = __fadd_rn(__fmul_rn(v[i], dec[i]), xi[i]);
            // s = (v - vth > 0) ? 1 : 0
            float d = __fsub_rn(vv, vth[i]);
            bool fire = (d > 0.0f);
            so[i] = fire ? 1.0f : 0.0f;
            // v = v - s*vth: s=1 -> exactly d (fl(v - vth)); s=0 -> exactly vv
            v[i] = fire ? d : vv;
        }
        s.x = so[0]; s.y = so[1]; s.z = so[2]; s.w = so[3];
        __builtin_nontemporal_store(s, &o4[base4 + (size_t)t * LIF_CHW4]);
    }
}

extern "C" void kernel_launch(void* const* d_in, const int* in_sizes, int n_in,
                              void* d_out, int out_size, void* d_ws, size_t ws_size,
                              hipStream_t stream) {
    const float* x         = (const float*)d_in[0];
    const float* vth_raw   = (const float*)d_in[1];
    const float* decay_raw = (const float*)d_in[2];
    float* out             = (float*)d_out;

    const int total_threads = LIF_B * LIF_CHW4;   // 262144
    const int block = 256;
    const int grid = total_threads / block;       // 1024 blocks = 4 blocks/CU
    HR_HLIFLayer2D_kernel<<<grid, block, 0, stream>>>(x, vth_raw, decay_raw, out);
}

// Round 6
// 235.214 us; speedup vs baseline: 1.0264x; 1.0092x over previous
//
#include <hip/hip_runtime.h>
#include <math.h>

// HR_HLIFLayer2D: leaky integrate-and-fire over T=32 timesteps.
// x: (B=16, T=32, C=64, H=32, W=32) f32; vth_raw/decay_raw: (C,H,W) f32.
// out: spikes (B,T,C,H,W) f32 in {0.0, 1.0}.
//
// R6: batch-8 double-buffered pipeline. R5 showed sched_barrier alone can't
// stop the register allocator from serializing a rotating prefetch (it
// recycles destination quads with early waitcnts; VGPR stayed 44). A batch
// of 8 loads whose results are ALL consumed after the batch forces 32
// simultaneously-live VGPRs -> the 8 loads must genuinely coexist in flight.
// 8 KB/wave outstanding, one waitcnt per 8 timesteps, 16 waves/CU.
//
// Numerics: recurrence uses explicit __fmul_rn/__fadd_rn/__fsub_rn to match
// the fp32 reference op order exactly (no FMA contraction). Params computed
// with double transcendentals, rounded once to fp32 per reference op sequence.
// absmax == 0.0 verified in R1-R5 with this exact scheme.

#define LIF_B    16
#define LIF_T    32
#define LIF_CHW  65536   // 64*32*32
#define LIF_CHW4 16384   // CHW / 4
#define BATCH    8
#define NBATCH   (LIF_T / BATCH)   // 4

typedef float vf4 __attribute__((ext_vector_type(4)));

__global__ __launch_bounds__(256, 4) void HR_HLIFLayer2D_kernel(
    const float* __restrict__ x,
    const float* __restrict__ vth_raw,
    const float* __restrict__ decay_raw,
    float* __restrict__ out)
{
    const int g = blockIdx.x * 256 + threadIdx.x;   // [0, B*CHW4)
    const int b = g >> 14;                          // g / CHW4
    const int j = g & (LIF_CHW4 - 1);               // float4 index within CHW

    const size_t base4 = (size_t)b * (LIF_T * LIF_CHW4) + (size_t)j;
    const vf4* __restrict__ x4 = reinterpret_cast<const vf4*>(x);
    vf4* __restrict__ o4 = reinterpret_cast<vf4*>(out);

    // Double buffer: 2 x 8 float4 = 64 VGPRs. All 8 results of a batch are
    // consumed only after the whole batch is issued -> RA cannot collapse it.
    vf4 buf[2][BATCH];

    // Prologue: issue batch 0 (overlaps the f64 param math below).
#pragma unroll
    for (int i = 0; i < BATCH; ++i)
        buf[0][i] = x4[base4 + (size_t)i * LIF_CHW4];
    __builtin_amdgcn_sched_barrier(0);

    const vf4 vr4 = reinterpret_cast<const vf4*>(vth_raw)[j];
    const vf4 dr4 = reinterpret_cast<const vf4*>(decay_raw)[j];
    const float vrr[4] = {vr4.x, vr4.y, vr4.z, vr4.w};
    const float drr[4] = {dr4.x, dr4.y, dr4.z, dr4.w};

    float vth[4], dec[4];
#pragma unroll
    for (int i = 0; i < 4; ++i) {
        // vth = softplus(vth_raw*0.1 + 0.5) + 0.01, fp32 rounding sequence
        float a  = __fmul_rn(vrr[i], 0.1f);
        float bb = __fadd_rn(a, 0.5f);
        double sp = log1p(exp((double)bb));          // correctly-rounded softplus
        vth[i] = __fadd_rn((float)sp, 0.01f);

        // decay = clip(sigmoid(decay_raw*0.1 + 2.0), 0, 0.99)
        float z = __fmul_rn(drr[i], 0.1f);
        float w = __fadd_rn(z, 2.0f);
        double sg = 1.0 / (1.0 + exp(-(double)w));
        float sgf = (float)sg;
        sgf = fminf(fmaxf(sgf, 0.0f), 0.99f);        // never binds in practice
        dec[i] = sgf;
    }

    float v[4] = {0.f, 0.f, 0.f, 0.f};

#pragma unroll
    for (int kb = 0; kb < NBATCH; ++kb) {
        const int cur = kb & 1;

        // Prefetch next batch (8 back-to-back dwordx4 loads), pinned so the
        // scheduler cannot sink them below this batch's compute/stores.
        if (kb + 1 < NBATCH) {
#pragma unroll
            for (int i = 0; i < BATCH; ++i)
                buf[cur ^ 1][i] =
                    x4[base4 + (size_t)((kb + 1) * BATCH + i) * LIF_CHW4];
            __builtin_amdgcn_sched_barrier(0);
        }

        // Consume current batch: 8 recurrence steps + 8 NT stores.
#pragma unroll
        for (int i = 0; i < BATCH; ++i) {
            const int t = kb * BATCH + i;
            const vf4 xt = buf[cur][i];
            const float xi[4] = {xt.x, xt.y, xt.z, xt.w};
            vf4 s;
            float so[4];
#pragma unroll
            for (int e = 0; e < 4; ++e) {
                // v = v*decay + x_t   (separate mul, add — match ref rounding)
                float vv = __fadd_rn(__fmul_rn(v[e], dec[e]), xi[e]);
                // s = (v - vth > 0) ? 1 : 0
                float d = __fsub_rn(vv, vth[e]);
                bool fire = (d > 0.0f);
                so[e] = fire ? 1.0f : 0.0f;
                // v = v - s*vth: s=1 -> exactly d; s=0 -> exactly vv
                v[e] = fire ? d : vv;
            }
            s.x = so[0]; s.y = so[1]; s.z = so[2]; s.w = so[3];
            __builtin_nontemporal_store(s, &o4[base4 + (size_t)t * LIF_CHW4]);
        }
    }
}

extern "C" void kernel_launch(void* const* d_in, const int* in_sizes, int n_in,
                              void* d_out, int out_size, void* d_ws, size_t ws_size,
                              hipStream_t stream) {
    const float* x         = (const float*)d_in[0];
    const float* vth_raw   = (const float*)d_in[1];
    const float* decay_raw = (const float*)d_in[2];
    float* out             = (float*)d_out;

    const int total_threads = LIF_B * LIF_CHW4;   // 262144
    const int block = 256;
    const int grid = total_threads / block;       // 1024 blocks = 4 blocks/CU
    HR_HLIFLayer2D_kernel<<<grid, block, 0, stream>>>(x, vth_raw, decay_raw, out);
}